// Round 2
// baseline (480.635 us; speedup 1.0000x reference)
//
#include <hip/hip_runtime.h>

#define B_ROWS 1024
#define D_DIM  512
#define C_CLS  100000
#define N_TILES 782     // ceil(100000/128)
#define GRID_NJ 98      // 98*8 = 784 >= 782 (XCD-swizzle padding, 16 idle blocks)

typedef unsigned short u16;
typedef __attribute__((ext_vector_type(8))) short bf16x8;
typedef __attribute__((ext_vector_type(4))) float f32x4;

__device__ __forceinline__ u16 f2bf(float f) {
  unsigned u = __float_as_uint(f);
  u += 0x7fffu + ((u >> 16) & 1u);   // round-to-nearest-even
  return (u16)(u >> 16);
}

// pack 8 fp32 -> 8 bf16 (RTZ high-16) via v_perm_b32 (fallback path only)
__device__ __forceinline__ bf16x8 pack8(float4 a, float4 b) {
  union { bf16x8 v; unsigned u[4]; } r;
  r.u[0] = __builtin_amdgcn_perm(__float_as_uint(a.y), __float_as_uint(a.x), 0x07060302u);
  r.u[1] = __builtin_amdgcn_perm(__float_as_uint(a.w), __float_as_uint(a.z), 0x07060302u);
  r.u[2] = __builtin_amdgcn_perm(__float_as_uint(b.y), __float_as_uint(b.x), 0x07060302u);
  r.u[3] = __builtin_amdgcn_perm(__float_as_uint(b.w), __float_as_uint(b.z), 0x07060302u);
  return r.v;
}

__device__ __forceinline__ void gll16(const void* g, void* l) {
  __builtin_amdgcn_global_load_lds(
      (const __attribute__((address_space(1))) unsigned int*)g,
      (__attribute__((address_space(3))) unsigned int*)l, 16, 0, 0);
}

// ---------------- fast path: prep (features + weights -> normalized bf16) ---
// One wave per row over [features ; weight]: L2-normalize the 512-float row
// IN FP32, then emit bf16 (RNE). MFMA output becomes the cosine directly.
__global__ void prep_kernel(const float* __restrict__ feat,
                            const float* __restrict__ wt,
                            u16* __restrict__ fn, u16* __restrict__ wb,
                            float* __restrict__ psum)
{
  const int row  = blockIdx.x * 4 + (threadIdx.x >> 6);
  const int lane = threadIdx.x & 63;
  const float* src = (row < B_ROWS) ? feat + (size_t)row * D_DIM
                                    : wt + (size_t)(row - B_ROWS) * D_DIM;
  u16* dst = (row < B_ROWS) ? fn + (size_t)row * D_DIM
                            : wb + (size_t)(row - B_ROWS) * D_DIM;
  const float4* r = (const float4*)src;
  float4 v0 = r[lane];
  float4 v1 = r[lane + 64];
  float ss = v0.x*v0.x + v0.y*v0.y + v0.z*v0.z + v0.w*v0.w
           + v1.x*v1.x + v1.y*v1.y + v1.z*v1.z + v1.w*v1.w;
#pragma unroll
  for (int m = 1; m < 64; m <<= 1) ss += __shfl_xor(ss, m);
  const float inv = 1.0f / fmaxf(sqrtf(ss), 1e-12f);
  ushort4 o0, o1;
  o0.x = f2bf(v0.x * inv); o0.y = f2bf(v0.y * inv);
  o0.z = f2bf(v0.z * inv); o0.w = f2bf(v0.w * inv);
  o1.x = f2bf(v1.x * inv); o1.y = f2bf(v1.y * inv);
  o1.z = f2bf(v1.z * inv); o1.w = f2bf(v1.w * inv);
  ushort4* od = (ushort4*)dst;
  od[lane]      = o0;
  od[lane + 64] = o1;
  if (row < B_ROWS && lane == 0) psum[row] = 0.0f;
}

// ---------------- fast path: pure m97-structure GEMM ------------------------
// Both operands staged via global_load_lds width=16 (pre-normalized bf16).
// K-loop body: 4 gll16 + barrier + 8 ds_read_b128 + 16 MFMA + barrier.
__global__ __launch_bounds__(256, 4) void arc_gemm_pre(
    const u16* __restrict__ fn, const u16* __restrict__ wb,
    const int* __restrict__ targets, float* __restrict__ psum,
    float* __restrict__ tlogit)
{
  __shared__ u16 As[128 * 32];
  __shared__ u16 Ws[128 * 32];
  __shared__ int tg[128];

  const int tid = threadIdx.x;
  const int bx  = blockIdx.x;
  const int xcd = bx & 7;
  const int l   = bx >> 3;
  const int tile_ni = (l >> 3) * 8 + xcd;
  if (tile_ni >= N_TILES) return;
  const int tile_m = (l & 7) << 7;
  const int tile_n = tile_ni << 7;

  if (tid < 128) tg[tid] = targets[tile_m + tid];

  const int wave = tid >> 6, lane = tid & 63;
  const int wm = wave >> 1, wno = wave & 1;
  const int quad = lane >> 4, l15 = lane & 15;

  f32x4 acc[4][4] = {};

  // Staging thread t owns rows (t>>2, t>>2+64), XOR-swizzled k-chunk
  // (swizzle on the per-lane GLOBAL src addr; gll16 LDS dest stays linear).
  const int srow   = tid >> 2;
  const int schunk = (tid & 3) ^ ((tid >> 3) & 3);
  const u16* Ag = fn + (size_t)(tile_m + srow) * D_DIM + schunk * 8;
  const int wr0 = tile_n + srow;
  const int wr1 = wr0 + 64;
  const u16* Wg0 = wb + (size_t)min(wr0, C_CLS - 1) * D_DIM + schunk * 8;
  const u16* Wg1 = wb + (size_t)min(wr1, C_CLS - 1) * D_DIM + schunk * 8;
  u16* Asd0 = As + tid * 8;
  u16* Asd1 = As + 2048 + tid * 8;
  u16* Wsd0 = Ws + tid * 8;
  u16* Wsd1 = Ws + 2048 + tid * 8;

  const int rsw = (quad ^ ((l15 >> 1) & 3)) * 8;
  const u16* ApA = As + (wm * 64 + l15) * 32 + rsw;
  const u16* ApW = Ws + (wno * 64 + l15) * 32 + rsw;

  for (int k0 = 0; k0 < D_DIM; k0 += 32) {
    gll16(Ag + k0, Asd0);
    gll16(Ag + 64 * D_DIM + k0, Asd1);
    gll16(Wg0 + k0, Wsd0);
    gll16(Wg1 + k0, Wsd1);
    __syncthreads();
    bf16x8 af[4], wf[4];
#pragma unroll
    for (int r = 0; r < 4; r++) af[r] = *(const bf16x8*)(ApA + r * 16 * 32);
#pragma unroll
    for (int r = 0; r < 4; r++) wf[r] = *(const bf16x8*)(ApW + r * 16 * 32);
#pragma unroll
    for (int rm = 0; rm < 4; rm++)
#pragma unroll
      for (int rn = 0; rn < 4; rn++)
        acc[rm][rn] = __builtin_amdgcn_mfma_f32_16x16x32_bf16(
            af[rm], wf[rn], acc[rm][rn], 0, 0, 0);
    __syncthreads();
  }

  const float Sc   = 30.0f;
  const float COSM = 0.9553364891256060f;
  const float SINM = 0.2955202066613396f;
  const float THc  = -0.9553364891256060f;
  const float MMc  = 0.0886560619984019f;

#pragma unroll
  for (int rm = 0; rm < 4; rm++) {
#pragma unroll
    for (int reg = 0; reg < 4; reg++) {
      const int bl = wm * 64 + rm * 16 + quad * 4 + reg;
      const int b = tile_m + bl;
      const int tgt = tg[bl];
      float s = 0.0f;
#pragma unroll
      for (int rn = 0; rn < 4; rn++) {
        const int c = tile_n + wno * 64 + rn * 16 + l15;
        const float cosv = acc[rm][rn][reg];
        float logit = Sc * cosv;
        if (c == tgt) {
          const float sine = sqrtf(fmaxf(1.0f - cosv * cosv, 0.0f));
          float phi = cosv * COSM - sine * SINM;
          phi = (cosv > THc) ? phi : (cosv - MMc);
          logit = Sc * phi;
          tlogit[b] = logit;
        }
        s += (c < C_CLS) ? __expf(logit - 30.0f) : 0.0f;
      }
      s += __shfl_xor(s, 1);
      s += __shfl_xor(s, 2);
      s += __shfl_xor(s, 4);
      s += __shfl_xor(s, 8);
      if (l15 == 0) atomicAdd(psum + b, s);
    }
  }
}

// ---------------- fallback path (round-0 proven kernels) --------------------
__global__ void norm_feat_kernel(const float* __restrict__ in,
                                 u16* __restrict__ out,
                                 float* __restrict__ psum)
{
  const int row  = blockIdx.x * 4 + (threadIdx.x >> 6);
  const int lane = threadIdx.x & 63;
  const float4* r = (const float4*)(in + (size_t)row * D_DIM);
  float4 v0 = r[lane];
  float4 v1 = r[lane + 64];
  float ss = v0.x*v0.x + v0.y*v0.y + v0.z*v0.z + v0.w*v0.w
           + v1.x*v1.x + v1.y*v1.y + v1.z*v1.z + v1.w*v1.w;
#pragma unroll
  for (int m = 1; m < 64; m <<= 1) ss += __shfl_xor(ss, m);
  const float inv = 1.0f / fmaxf(sqrtf(ss), 1e-12f);
  ushort4 o0, o1;
  o0.x = f2bf(v0.x * inv); o0.y = f2bf(v0.y * inv);
  o0.z = f2bf(v0.z * inv); o0.w = f2bf(v0.w * inv);
  o1.x = f2bf(v1.x * inv); o1.y = f2bf(v1.y * inv);
  o1.z = f2bf(v1.z * inv); o1.w = f2bf(v1.w * inv);
  ushort4* orow = (ushort4*)(out + (size_t)row * D_DIM);
  orow[lane]      = o0;
  orow[lane + 64] = o1;
  if (lane == 0) psum[row] = 0.0f;
}

__global__ __launch_bounds__(256, 4) void arc_gemm_raw(
    const u16* __restrict__ fn, const float* __restrict__ wt,
    const int* __restrict__ targets, float* __restrict__ psum,
    float* __restrict__ tlogit)
{
  __shared__ u16 As[128 * 32];
  __shared__ u16 Ws[128 * 32];
  __shared__ int tg[128];
  __shared__ float winv[128];

  const int tid = threadIdx.x;
  const int bx  = blockIdx.x;
  const int xcd = bx & 7;
  const int l   = bx >> 3;
  const int tile_ni = (l >> 3) * 8 + xcd;
  if (tile_ni >= N_TILES) return;
  const int tile_m = (l & 7) << 7;
  const int tile_n = tile_ni << 7;

  if (tid < 128) tg[tid] = targets[tile_m + tid];

  const int wave = tid >> 6, lane = tid & 63;
  const int wm = wave >> 1, wno = wave & 1;
  const int quad = lane >> 4, l15 = lane & 15;

  f32x4 acc[4][4] = {};

  const int srow   = tid >> 2;
  const int schunk = (tid & 3) ^ ((tid >> 3) & 3);
  const u16* Ag = fn + (size_t)(tile_m + srow) * D_DIM + schunk * 8;
  u16* Asd0 = As + tid * 8;
  u16* Asd1 = As + 2048 + tid * 8;
  const int wr0 = tile_n + srow;
  const int wr1 = wr0 + 64;
  const float* Wg0 = wt + (size_t)min(wr0, C_CLS - 1) * D_DIM + schunk * 8;
  const float* Wg1 = wt + (size_t)min(wr1, C_CLS - 1) * D_DIM + schunk * 8;
  u16* Wsd0 = Ws + tid * 8;
  u16* Wsd1 = Ws + 2048 + tid * 8;

  const int rsw = (quad ^ ((l15 >> 1) & 3)) * 8;
  const u16* ApA = As + (wm * 64 + l15) * 32 + rsw;
  const u16* ApW = Ws + (wno * 64 + l15) * 32 + rsw;

  float ssq0 = 0.0f, ssq1 = 0.0f;

  for (int k0 = 0; k0 < D_DIM; k0 += 32) {
    const float4 wa = *(const float4*)(Wg0 + k0);
    const float4 wb2 = *(const float4*)(Wg0 + k0 + 4);
    const float4 wc = *(const float4*)(Wg1 + k0);
    const float4 wd = *(const float4*)(Wg1 + k0 + 4);
    gll16(Ag + k0, Asd0);
    gll16(Ag + 64 * D_DIM + k0, Asd1);
    ssq0 += wa.x*wa.x + wa.y*wa.y + wa.z*wa.z + wa.w*wa.w
          + wb2.x*wb2.x + wb2.y*wb2.y + wb2.z*wb2.z + wb2.w*wb2.w;
    ssq1 += wc.x*wc.x + wc.y*wc.y + wc.z*wc.z + wc.w*wc.w
          + wd.x*wd.x + wd.y*wd.y + wd.z*wd.z + wd.w*wd.w;
    *(bf16x8*)Wsd0 = pack8(wa, wb2);
    *(bf16x8*)Wsd1 = pack8(wc, wd);
    __syncthreads();
    bf16x8 af[4], wf[4];
#pragma unroll
    for (int r = 0; r < 4; r++) af[r] = *(const bf16x8*)(ApA + r * 16 * 32);
#pragma unroll
    for (int r = 0; r < 4; r++) wf[r] = *(const bf16x8*)(ApW + r * 16 * 32);
#pragma unroll
    for (int rm = 0; rm < 4; rm++)
#pragma unroll
      for (int rn = 0; rn < 4; rn++)
        acc[rm][rn] = __builtin_amdgcn_mfma_f32_16x16x32_bf16(
            af[rm], wf[rn], acc[rm][rn], 0, 0, 0);
    __syncthreads();
  }

  ssq0 += __shfl_xor(ssq0, 1); ssq0 += __shfl_xor(ssq0, 2);
  ssq1 += __shfl_xor(ssq1, 1); ssq1 += __shfl_xor(ssq1, 2);
  if ((tid & 3) == 0) {
    winv[srow]      = 1.0f / fmaxf(sqrtf(ssq0), 1e-12f);
    winv[srow + 64] = 1.0f / fmaxf(sqrtf(ssq1), 1e-12f);
  }
  __syncthreads();

  float wiv[4];
#pragma unroll
  for (int rn = 0; rn < 4; rn++) wiv[rn] = winv[wno * 64 + rn * 16 + l15];

  const float Sc   = 30.0f;
  const float COSM = 0.9553364891256060f;
  const float SINM = 0.2955202066613396f;
  const float THc  = -0.9553364891256060f;
  const float MMc  = 0.0886560619984019f;

#pragma unroll
  for (int rm = 0; rm < 4; rm++) {
#pragma unroll
    for (int reg = 0; reg < 4; reg++) {
      const int bl = wm * 64 + rm * 16 + quad * 4 + reg;
      const int b = tile_m + bl;
      const int tgt = tg[bl];
      float s = 0.0f;
#pragma unroll
      for (int rn = 0; rn < 4; rn++) {
        const int c = tile_n + wno * 64 + rn * 16 + l15;
        const float cosv = acc[rm][rn][reg] * wiv[rn];
        float logit = Sc * cosv;
        if (c == tgt) {
          const float sine = sqrtf(fmaxf(1.0f - cosv * cosv, 0.0f));
          float phi = cosv * COSM - sine * SINM;
          phi = (cosv > THc) ? phi : (cosv - MMc);
          logit = Sc * phi;
          tlogit[b] = logit;
        }
        s += (c < C_CLS) ? __expf(logit - 30.0f) : 0.0f;
      }
      s += __shfl_xor(s, 1);
      s += __shfl_xor(s, 2);
      s += __shfl_xor(s, 4);
      s += __shfl_xor(s, 8);
      if (l15 == 0) atomicAdd(psum + b, s);
    }
  }
}

__global__ void finalize_loss(const float* __restrict__ psum,
                              const float* __restrict__ tlogit,
                              float* __restrict__ out)
{
  const int tid = threadIdx.x;
  float s = 0.0f;
  for (int i = tid; i < B_ROWS; i += 256)
    s += 30.0f + logf(psum[i]) - tlogit[i];
#pragma unroll
  for (int m = 1; m < 64; m <<= 1) s += __shfl_xor(s, m);
  __shared__ float red[4];
  if ((tid & 63) == 0) red[tid >> 6] = s;
  __syncthreads();
  if (tid == 0) out[0] = (red[0] + red[1] + red[2] + red[3]) * (1.0f / B_ROWS);
}

extern "C" void kernel_launch(void* const* d_in, const int* in_sizes, int n_in,
                              void* d_out, int out_size, void* d_ws, size_t ws_size,
                              hipStream_t stream) {
  const float* feat = (const float*)d_in[0];
  const float* wt   = (const float*)d_in[1];
  const int*   tgt  = (const int*)d_in[2];
  float* out = (float*)d_out;
  char* ws = (char*)d_ws;

  const size_t fn_bytes = (size_t)B_ROWS * D_DIM * 2;        // 1 MB
  const size_t wb_bytes = (size_t)C_CLS * D_DIM * 2;         // 102.4 MB
  const size_t tail     = 2 * (size_t)B_ROWS * sizeof(float);

  if (ws_size >= fn_bytes + wb_bytes + tail) {
    // fast path: W pre-normalized to bf16 in workspace
    u16* fn = (u16*)ws;
    u16* wb = (u16*)(ws + fn_bytes);
    float* psum = (float*)(ws + fn_bytes + wb_bytes);
    float* tlogit = psum + B_ROWS;
    prep_kernel<<<(B_ROWS + C_CLS) / 4, 256, 0, stream>>>(feat, wt, fn, wb, psum);
    arc_gemm_pre<<<GRID_NJ * 8 * 8, 256, 0, stream>>>(fn, wb, tgt, psum, tlogit);
    finalize_loss<<<1, 256, 0, stream>>>(psum, tlogit, out);
  } else {
    // fallback: proven round-0 path (~1 MB workspace)
    u16* fn = (u16*)ws;
    float* psum = (float*)(ws + fn_bytes);
    float* tlogit = psum + B_ROWS;
    norm_feat_kernel<<<B_ROWS / 4, 256, 0, stream>>>(feat, fn, psum);
    arc_gemm_raw<<<GRID_NJ * 8 * 8, 256, 0, stream>>>(fn, wt, tgt, psum, tlogit);
    finalize_loss<<<1, 256, 0, stream>>>(psum, tlogit, out);
  }
}

// Round 3
// 425.310 us; speedup vs baseline: 1.1301x; 1.1301x over previous
//
#include <hip/hip_runtime.h>

#define B_ROWS 1024
#define D_DIM  512
#define C_CLS  100000
#define N_TILES 782     // ceil(100000/128)
#define GRID_NJ 98      // 98*8 = 784 >= 782 (XCD-swizzle padding, 16 idle blocks)

typedef unsigned short u16;
typedef __attribute__((ext_vector_type(8))) short bf16x8;
typedef __attribute__((ext_vector_type(4))) float f32x4;

__device__ __forceinline__ u16 f2bf(float f) {
  unsigned u = __float_as_uint(f);
  u += 0x7fffu + ((u >> 16) & 1u);   // round-to-nearest-even
  return (u16)(u >> 16);
}

// pack 8 fp32 -> 8 bf16 (RTZ high-16) via v_perm_b32 (fallback path only)
__device__ __forceinline__ bf16x8 pack8(float4 a, float4 b) {
  union { bf16x8 v; unsigned u[4]; } r;
  r.u[0] = __builtin_amdgcn_perm(__float_as_uint(a.y), __float_as_uint(a.x), 0x07060302u);
  r.u[1] = __builtin_amdgcn_perm(__float_as_uint(a.w), __float_as_uint(a.z), 0x07060302u);
  r.u[2] = __builtin_amdgcn_perm(__float_as_uint(b.y), __float_as_uint(b.x), 0x07060302u);
  r.u[3] = __builtin_amdgcn_perm(__float_as_uint(b.w), __float_as_uint(b.z), 0x07060302u);
  return r.v;
}

__device__ __forceinline__ void gll16(const void* g, void* l) {
  __builtin_amdgcn_global_load_lds(
      (const __attribute__((address_space(1))) unsigned int*)g,
      (__attribute__((address_space(3))) unsigned int*)l, 16, 0, 0);
}

// ---------------- fast path: prep (features + weights -> normalized bf16) ---
// Grid-stride (2048 blocks, one wave per row per iteration): L2-normalize the
// 512-float row IN FP32, emit bf16 (RNE). MFMA output becomes cosine directly.
__global__ __launch_bounds__(256) void prep_kernel(
    const float* __restrict__ feat, const float* __restrict__ wt,
    u16* __restrict__ fn, u16* __restrict__ wb, float* __restrict__ psum)
{
  const int lane = threadIdx.x & 63;
  const int wid  = blockIdx.x * 4 + (threadIdx.x >> 6);
  const int nw   = gridDim.x * 4;
  for (int row = wid; row < B_ROWS + C_CLS; row += nw) {
    const float* src = (row < B_ROWS) ? feat + (size_t)row * D_DIM
                                      : wt + (size_t)(row - B_ROWS) * D_DIM;
    u16* dst = (row < B_ROWS) ? fn + (size_t)row * D_DIM
                              : wb + (size_t)(row - B_ROWS) * D_DIM;
    const float4* r = (const float4*)src;
    float4 v0 = r[lane];
    float4 v1 = r[lane + 64];
    float ss = v0.x*v0.x + v0.y*v0.y + v0.z*v0.z + v0.w*v0.w
             + v1.x*v1.x + v1.y*v1.y + v1.z*v1.z + v1.w*v1.w;
#pragma unroll
    for (int m = 1; m < 64; m <<= 1) ss += __shfl_xor(ss, m);
    const float inv = 1.0f / fmaxf(sqrtf(ss), 1e-12f);
    ushort4 o0, o1;
    o0.x = f2bf(v0.x * inv); o0.y = f2bf(v0.y * inv);
    o0.z = f2bf(v0.z * inv); o0.w = f2bf(v0.w * inv);
    o1.x = f2bf(v1.x * inv); o1.y = f2bf(v1.y * inv);
    o1.z = f2bf(v1.z * inv); o1.w = f2bf(v1.w * inv);
    ushort4* od = (ushort4*)dst;
    od[lane]      = o0;
    od[lane + 64] = o1;
    if (row < B_ROWS && lane == 0) psum[row] = 0.0f;
  }
}

// ---------------- fast path: 128x128 / BK=64 MFMA GEMM ----------------------
// Both operands staged via global_load_lds width=16 (pre-normalized bf16).
// BK=64: 8 K-iterations, each {8 gll16 -> barrier -> 2x(8 ds_read_b128 +
// 16 MFMA) -> barrier}. 32 MFMA per barrier-drain (2x the BK=32 version).
// LDS swizzle: row has 8 16B-chunks; stored slot = chunk ^ (row&7), so
// ds_read_b128 at fixed logical chunk across 16 rows spreads over 8 slots.
__global__ __launch_bounds__(256, 4) void arc_gemm_pre(
    const u16* __restrict__ fn, const u16* __restrict__ wb,
    const int* __restrict__ targets, float* __restrict__ psum,
    float* __restrict__ tlogit)
{
  __shared__ u16 As[128 * 64];
  __shared__ u16 Ws[128 * 64];
  __shared__ int tg[128];
  __shared__ float pr[256];

  const int tid = threadIdx.x;
  const int bx  = blockIdx.x;
  const int xcd = bx & 7;
  const int l   = bx >> 3;
  const int tile_ni = (l >> 3) * 8 + xcd;
  if (tile_ni >= N_TILES) return;
  const int tile_m = (l & 7) << 7;
  const int tile_n = tile_ni << 7;

  if (tid < 128) tg[tid] = targets[tile_m + tid];

  const int wave = tid >> 6, lane = tid & 63;
  const int wm = wave >> 1, wno = wave & 1;
  const int quad = lane >> 4, l15 = lane & 15;

  f32x4 acc[4][4] = {};

  // Staging: linear slot s = i*256 + tid (i=0..3) covers 128 rows x 8 slots.
  // row = s>>3, slot = s&7, global chunk = slot ^ (row&7). Since i*256 adds
  // a multiple of 8 to row and 0 to slot, chunk is i-invariant -> one base
  // pointer per operand, +i*32 rows offset. gll16 LDS dest stays linear.
  const int srow8  = tid >> 3;                    // row within 32-row group
  const int schunk = (tid & 7) ^ (srow8 & 7);
  const u16* Abase = fn + (size_t)(tile_m + srow8) * D_DIM + schunk * 8;
  unsigned woff[4];
#pragma unroll
  for (int i = 0; i < 4; i++) {
    const int wrow = tile_n + i * 32 + srow8;
    woff[i] = (unsigned)min(wrow, C_CLS - 1) * D_DIM;   // clamp pad rows
  }
  const u16* Wchunk = wb + schunk * 8;
  u16* Asd = As + tid * 8;
  u16* Wsd = Ws + tid * 8;

  // read side: row = (wm|wno)*64 + r*16 + l15 -> row&7 == l15&7
  const u16* ApA = As + (wm * 64 + l15) * 64;
  const u16* ApW = Ws + (wno * 64 + l15) * 64;
  const int sw0 = ((quad    ) ^ (l15 & 7)) * 8;   // k-half 0: chunks 0..3
  const int sw1 = ((quad ^ 4) ^ (l15 & 7)) * 8;   // k-half 1: chunks 4..7

  for (int k0 = 0; k0 < D_DIM; k0 += 64) {
#pragma unroll
    for (int i = 0; i < 4; i++) {
      gll16(Abase + k0 + i * 32 * D_DIM, Asd + i * 2048);
      gll16(Wchunk + woff[i] + k0,       Wsd + i * 2048);
    }
    __syncthreads();               // compiler emits vmcnt(0) drain here
    {
      bf16x8 af[4], wf[4];
#pragma unroll
      for (int r = 0; r < 4; r++) af[r] = *(const bf16x8*)(ApA + r * 1024 + sw0);
#pragma unroll
      for (int r = 0; r < 4; r++) wf[r] = *(const bf16x8*)(ApW + r * 1024 + sw0);
#pragma unroll
      for (int rm = 0; rm < 4; rm++)
#pragma unroll
        for (int rn = 0; rn < 4; rn++)
          acc[rm][rn] = __builtin_amdgcn_mfma_f32_16x16x32_bf16(
              af[rm], wf[rn], acc[rm][rn], 0, 0, 0);
    }
    __builtin_amdgcn_sched_barrier(0);  // cap frag liveness: no cross-half mix
    {
      bf16x8 af[4], wf[4];
#pragma unroll
      for (int r = 0; r < 4; r++) af[r] = *(const bf16x8*)(ApA + r * 1024 + sw1);
#pragma unroll
      for (int r = 0; r < 4; r++) wf[r] = *(const bf16x8*)(ApW + r * 1024 + sw1);
#pragma unroll
      for (int rm = 0; rm < 4; rm++)
#pragma unroll
        for (int rn = 0; rn < 4; rn++)
          acc[rm][rn] = __builtin_amdgcn_mfma_f32_16x16x32_bf16(
              af[rm], wf[rn], acc[rm][rn], 0, 0, 0);
    }
    __syncthreads();
  }

  const float Sc   = 30.0f;
  const float COSM = 0.9553364891256060f;
  const float SINM = 0.2955202066613396f;
  const float THc  = -0.9553364891256060f;
  const float MMc  = 0.0886560619984019f;

#pragma unroll
  for (int rm = 0; rm < 4; rm++) {
#pragma unroll
    for (int reg = 0; reg < 4; reg++) {
      const int bl = wm * 64 + rm * 16 + quad * 4 + reg;  // C/D row = M index
      const int b = tile_m + bl;
      const int tgt = tg[bl];
      float s = 0.0f;
#pragma unroll
      for (int rn = 0; rn < 4; rn++) {
        const int c = tile_n + wno * 64 + rn * 16 + l15;  // C/D col = N index
        const float cosv = acc[rm][rn][reg];              // already cosine
        float logit = Sc * cosv;
        if (c == tgt) {
          const float sine = sqrtf(fmaxf(1.0f - cosv * cosv, 0.0f));
          float phi = cosv * COSM - sine * SINM;
          phi = (cosv > THc) ? phi : (cosv - MMc);
          logit = Sc * phi;
          tlogit[b] = logit;   // exactly one lane in the grid owns (b, tgt)
        }
        s += (c < C_CLS) ? __expf(logit - 30.0f) : 0.0f;  // mask pad columns
      }
      s += __shfl_xor(s, 1);
      s += __shfl_xor(s, 2);
      s += __shfl_xor(s, 4);
      s += __shfl_xor(s, 8);
      if (l15 == 0) pr[wno * 128 + bl] = s;   // stage column-half partial
    }
  }
  __syncthreads();
  // fold the two column-half waves -> one device-scope atomic per row
  if (tid < 128) atomicAdd(psum + tile_m + tid, pr[tid] + pr[128 + tid]);
}

// ---------------- fallback path (round-0 proven kernels) --------------------
__global__ void norm_feat_kernel(const float* __restrict__ in,
                                 u16* __restrict__ out,
                                 float* __restrict__ psum)
{
  const int row  = blockIdx.x * 4 + (threadIdx.x >> 6);
  const int lane = threadIdx.x & 63;
  const float4* r = (const float4*)(in + (size_t)row * D_DIM);
  float4 v0 = r[lane];
  float4 v1 = r[lane + 64];
  float ss = v0.x*v0.x + v0.y*v0.y + v0.z*v0.z + v0.w*v0.w
           + v1.x*v1.x + v1.y*v1.y + v1.z*v1.z + v1.w*v1.w;
#pragma unroll
  for (int m = 1; m < 64; m <<= 1) ss += __shfl_xor(ss, m);
  const float inv = 1.0f / fmaxf(sqrtf(ss), 1e-12f);
  ushort4 o0, o1;
  o0.x = f2bf(v0.x * inv); o0.y = f2bf(v0.y * inv);
  o0.z = f2bf(v0.z * inv); o0.w = f2bf(v0.w * inv);
  o1.x = f2bf(v1.x * inv); o1.y = f2bf(v1.y * inv);
  o1.z = f2bf(v1.z * inv); o1.w = f2bf(v1.w * inv);
  ushort4* orow = (ushort4*)(out + (size_t)row * D_DIM);
  orow[lane]      = o0;
  orow[lane + 64] = o1;
  if (lane == 0) psum[row] = 0.0f;
}

__global__ __launch_bounds__(256, 4) void arc_gemm_raw(
    const u16* __restrict__ fn, const float* __restrict__ wt,
    const int* __restrict__ targets, float* __restrict__ psum,
    float* __restrict__ tlogit)
{
  __shared__ u16 As[128 * 32];
  __shared__ u16 Ws[128 * 32];
  __shared__ int tg[128];
  __shared__ float winv[128];

  const int tid = threadIdx.x;
  const int bx  = blockIdx.x;
  const int xcd = bx & 7;
  const int l   = bx >> 3;
  const int tile_ni = (l >> 3) * 8 + xcd;
  if (tile_ni >= N_TILES) return;
  const int tile_m = (l & 7) << 7;
  const int tile_n = tile_ni << 7;

  if (tid < 128) tg[tid] = targets[tile_m + tid];

  const int wave = tid >> 6, lane = tid & 63;
  const int wm = wave >> 1, wno = wave & 1;
  const int quad = lane >> 4, l15 = lane & 15;

  f32x4 acc[4][4] = {};

  const int srow   = tid >> 2;
  const int schunk = (tid & 3) ^ ((tid >> 3) & 3);
  const u16* Ag = fn + (size_t)(tile_m + srow) * D_DIM + schunk * 8;
  u16* Asd0 = As + tid * 8;
  u16* Asd1 = As + 2048 + tid * 8;
  const int wr0 = tile_n + srow;
  const int wr1 = wr0 + 64;
  const float* Wg0 = wt + (size_t)min(wr0, C_CLS - 1) * D_DIM + schunk * 8;
  const float* Wg1 = wt + (size_t)min(wr1, C_CLS - 1) * D_DIM + schunk * 8;
  u16* Wsd0 = Ws + tid * 8;
  u16* Wsd1 = Ws + 2048 + tid * 8;

  const int rsw = (quad ^ ((l15 >> 1) & 3)) * 8;
  const u16* ApA = As + (wm * 64 + l15) * 32 + rsw;
  const u16* ApW = Ws + (wno * 64 + l15) * 32 + rsw;

  float ssq0 = 0.0f, ssq1 = 0.0f;

  for (int k0 = 0; k0 < D_DIM; k0 += 32) {
    const float4 wa = *(const float4*)(Wg0 + k0);
    const float4 wb2 = *(const float4*)(Wg0 + k0 + 4);
    const float4 wc = *(const float4*)(Wg1 + k0);
    const float4 wd = *(const float4*)(Wg1 + k0 + 4);
    gll16(Ag + k0, Asd0);
    gll16(Ag + 64 * D_DIM + k0, Asd1);
    ssq0 += wa.x*wa.x + wa.y*wa.y + wa.z*wa.z + wa.w*wa.w
          + wb2.x*wb2.x + wb2.y*wb2.y + wb2.z*wb2.z + wb2.w*wb2.w;
    ssq1 += wc.x*wc.x + wc.y*wc.y + wc.z*wc.z + wc.w*wc.w
          + wd.x*wd.x + wd.y*wd.y + wd.z*wd.z + wd.w*wd.w;
    *(bf16x8*)Wsd0 = pack8(wa, wb2);
    *(bf16x8*)Wsd1 = pack8(wc, wd);
    __syncthreads();
    bf16x8 af[4], wf[4];
#pragma unroll
    for (int r = 0; r < 4; r++) af[r] = *(const bf16x8*)(ApA + r * 16 * 32);
#pragma unroll
    for (int r = 0; r < 4; r++) wf[r] = *(const bf16x8*)(ApW + r * 16 * 32);
#pragma unroll
    for (int rm = 0; rm < 4; rm++)
#pragma unroll
      for (int rn = 0; rn < 4; rn++)
        acc[rm][rn] = __builtin_amdgcn_mfma_f32_16x16x32_bf16(
            af[rm], wf[rn], acc[rm][rn], 0, 0, 0);
    __syncthreads();
  }

  ssq0 += __shfl_xor(ssq0, 1); ssq0 += __shfl_xor(ssq0, 2);
  ssq1 += __shfl_xor(ssq1, 1); ssq1 += __shfl_xor(ssq1, 2);
  if ((tid & 3) == 0) {
    winv[srow]      = 1.0f / fmaxf(sqrtf(ssq0), 1e-12f);
    winv[srow + 64] = 1.0f / fmaxf(sqrtf(ssq1), 1e-12f);
  }
  __syncthreads();

  float wiv[4];
#pragma unroll
  for (int rn = 0; rn < 4; rn++) wiv[rn] = winv[wno * 64 + rn * 16 + l15];

  const float Sc   = 30.0f;
  const float COSM = 0.9553364891256060f;
  const float SINM = 0.2955202066613396f;
  const float THc  = -0.9553364891256060f;
  const float MMc  = 0.0886560619984019f;

#pragma unroll
  for (int rm = 0; rm < 4; rm++) {
#pragma unroll
    for (int reg = 0; reg < 4; reg++) {
      const int bl = wm * 64 + rm * 16 + quad * 4 + reg;
      const int b = tile_m + bl;
      const int tgt = tg[bl];
      float s = 0.0f;
#pragma unroll
      for (int rn = 0; rn < 4; rn++) {
        const int c = tile_n + wno * 64 + rn * 16 + l15;
        const float cosv = acc[rm][rn][reg] * wiv[rn];
        float logit = Sc * cosv;
        if (c == tgt) {
          const float sine = sqrtf(fmaxf(1.0f - cosv * cosv, 0.0f));
          float phi = cosv * COSM - sine * SINM;
          phi = (cosv > THc) ? phi : (cosv - MMc);
          logit = Sc * phi;
          tlogit[b] = logit;
        }
        s += (c < C_CLS) ? __expf(logit - 30.0f) : 0.0f;
      }
      s += __shfl_xor(s, 1);
      s += __shfl_xor(s, 2);
      s += __shfl_xor(s, 4);
      s += __shfl_xor(s, 8);
      if (l15 == 0) atomicAdd(psum + b, s);
    }
  }
}

__global__ void finalize_loss(const float* __restrict__ psum,
                              const float* __restrict__ tlogit,
                              float* __restrict__ out)
{
  const int tid = threadIdx.x;
  float s = 0.0f;
  for (int i = tid; i < B_ROWS; i += 256)
    s += 30.0f + logf(psum[i]) - tlogit[i];
#pragma unroll
  for (int m = 1; m < 64; m <<= 1) s += __shfl_xor(s, m);
  __shared__ float red[4];
  if ((tid & 63) == 0) red[tid >> 6] = s;
  __syncthreads();
  if (tid == 0) out[0] = (red[0] + red[1] + red[2] + red[3]) * (1.0f / B_ROWS);
}

extern "C" void kernel_launch(void* const* d_in, const int* in_sizes, int n_in,
                              void* d_out, int out_size, void* d_ws, size_t ws_size,
                              hipStream_t stream) {
  const float* feat = (const float*)d_in[0];
  const float* wt   = (const float*)d_in[1];
  const int*   tgt  = (const int*)d_in[2];
  float* out = (float*)d_out;
  char* ws = (char*)d_ws;

  const size_t fn_bytes = (size_t)B_ROWS * D_DIM * 2;        // 1 MB
  const size_t wb_bytes = (size_t)C_CLS * D_DIM * 2;         // 102.4 MB
  const size_t tail     = 2 * (size_t)B_ROWS * sizeof(float);

  if (ws_size >= fn_bytes + wb_bytes + tail) {
    // fast path: W pre-normalized to bf16 in workspace
    u16* fn = (u16*)ws;
    u16* wb = (u16*)(ws + fn_bytes);
    float* psum = (float*)(ws + fn_bytes + wb_bytes);
    float* tlogit = psum + B_ROWS;
    prep_kernel<<<2048, 256, 0, stream>>>(feat, wt, fn, wb, psum);
    arc_gemm_pre<<<GRID_NJ * 8 * 8, 256, 0, stream>>>(fn, wb, tgt, psum, tlogit);
    finalize_loss<<<1, 256, 0, stream>>>(psum, tlogit, out);
  } else {
    // fallback: proven round-0 path (~1 MB workspace)
    u16* fn = (u16*)ws;
    float* psum = (float*)(ws + fn_bytes);
    float* tlogit = psum + B_ROWS;
    norm_feat_kernel<<<B_ROWS / 4, 256, 0, stream>>>(feat, fn, psum);
    arc_gemm_raw<<<GRID_NJ * 8 * 8, 256, 0, stream>>>(fn, wt, tgt, psum, tlogit);
    finalize_loss<<<1, 256, 0, stream>>>(psum, tlogit, out);
  }
}